// Round 13
// baseline (873.305 us; speedup 1.0000x reference)
//
#include <hip/hip_runtime.h>
#include <math.h>

#define DIM 32
#define NB 625          // buckets = N/256
#define CAP 5120        // per-bucket staging capacity

__device__ __forceinline__ unsigned short f2bf(float f) {
    unsigned u = __float_as_uint(f);
    u = (u + 0x7FFF + ((u >> 16) & 1)) >> 16;  // RNE
    return (unsigned short)u;
}
__device__ __forceinline__ float bf2f(unsigned short u) {
    return __uint_as_float(((unsigned)u) << 16);
}

// ---------------- init per-bucket staging cursors ----------------
__global__ void init_kernel(int* __restrict__ bcur) {
    int b = blockIdx.x * blockDim.x + threadIdx.x;
    if (b < NB) bcur[b] = b * CAP;
}

// ---------------- passA: bucket edges by col>>8 into staging (block=1024) ----------------
__global__ void passA_kernel(const int* __restrict__ row, const int* __restrict__ col,
                             const float* __restrict__ w, int* __restrict__ bcur,
                             unsigned long long* __restrict__ stage, int E) {
    __shared__ int hist[NB];
    __shared__ int lcur[NB];
    int base = blockIdx.x * 8192;
    for (int j = threadIdx.x; j < NB; j += 1024) hist[j] = 0;
    __syncthreads();
#pragma unroll
    for (int i = 0; i < 8; i++) {
        int e = base + i * 1024 + threadIdx.x;
        if (e < E) atomicAdd(&hist[col[e] >> 8], 1);
    }
    __syncthreads();
    for (int j = threadIdx.x; j < NB; j += 1024) {
        int h = hist[j];
        lcur[j] = h ? atomicAdd(&bcur[j], h) : 0;
    }
    __syncthreads();
#pragma unroll
    for (int i = 0; i < 8; i++) {
        int e = base + i * 1024 + threadIdx.x;
        if (e < E) {
            int c = col[e];
            int b = c >> 8;
            int pos = atomicAdd(&lcur[b], 1);
            if (pos < (b + 1) * CAP) {
                unsigned long long rec = ((unsigned long long)(unsigned)row[e] << 40)
                                       | ((unsigned long long)(unsigned)(c & 255) << 32)
                                       | (unsigned long long)__float_as_uint(w[e]);
                stage[pos] = rec;
            }
        }
    }
}

// ---------------- passB1: per-bucket col counts + weighted degree -> cnt, dinv ----------------
__global__ void passB1_kernel(const unsigned long long* __restrict__ stage,
                              const int* __restrict__ bcur,
                              int* __restrict__ cnt, float* __restrict__ dinv) {
    __shared__ int icnt[256];
    __shared__ float fdeg[256];
    int b = blockIdx.x;
    icnt[threadIdx.x] = 0;
    fdeg[threadIdx.x] = 0.0f;
    __syncthreads();
    int s0 = b * CAP;
    int m = min(bcur[b] - s0, CAP);
    for (int i = threadIdx.x; i < m; i += 256) {
        unsigned long long rec = stage[s0 + i];
        int cj = (int)((rec >> 32) & 255);
        float wf = __uint_as_float((unsigned)rec);
        atomicAdd(&icnt[cj], 1);
        atomicAdd(&fdeg[cj], wf);
    }
    __syncthreads();
    int c = b * 256 + threadIdx.x;
    cnt[c] = icnt[threadIdx.x];
    dinv[c] = rsqrtf(fdeg[threadIdx.x] + 1.0f);
}

// ---------------- scan over cnt -> ptr ----------------
__global__ void scan_block_kernel(const int* __restrict__ cnt, int* __restrict__ ptr,
                                  int* __restrict__ bsum, int N) {
    __shared__ int s[256];
    int i = blockIdx.x * 256 + threadIdx.x;
    int v = (i < N) ? cnt[i] : 0;
    s[threadIdx.x] = v;
    __syncthreads();
#pragma unroll
    for (int off = 1; off < 256; off <<= 1) {
        int t = (threadIdx.x >= off) ? s[threadIdx.x - off] : 0;
        __syncthreads();
        s[threadIdx.x] += t;
        __syncthreads();
    }
    if (i < N) ptr[i] = s[threadIdx.x] - v;
    if (threadIdx.x == 255) bsum[blockIdx.x] = s[255];
}

__global__ void scan_tops_kernel(int* __restrict__ bsum, int nb) {
    __shared__ int s[1024];
    int i = threadIdx.x;
    int v = (i < nb) ? bsum[i] : 0;
    s[i] = v;
    __syncthreads();
#pragma unroll
    for (int off = 1; off < 1024; off <<= 1) {
        int t = (i >= off) ? s[i - off] : 0;
        __syncthreads();
        s[i] += t;
        __syncthreads();
    }
    if (i < nb) bsum[i] = s[i] - v;  // exclusive
}

__global__ void scan_add_kernel(int* __restrict__ ptr, const int* __restrict__ bsum, int N, int E) {
    int i = blockIdx.x * blockDim.x + threadIdx.x;
    if (i < N) ptr[i] += bsum[i >> 8];
    if (i == 0) ptr[N] = E;
}

// ---------------- passB2: scatter staged records into CSR edat (LDS cursors) ----------------
// edat rec = r << 32 | fp32(nm)
__global__ void passB2_kernel(const unsigned long long* __restrict__ stage,
                              const int* __restrict__ bcur, const int* __restrict__ ptr,
                              const float* __restrict__ dinv,
                              unsigned long long* __restrict__ edat) {
    __shared__ int lcur[256];
    int b = blockIdx.x;
    lcur[threadIdx.x] = ptr[b * 256 + threadIdx.x];
    __syncthreads();
    int s0 = b * CAP;
    int m = min(bcur[b] - s0, CAP);
    for (int i = threadIdx.x; i < m; i += 256) {
        unsigned long long rec = stage[s0 + i];
        int r = (int)(rec >> 40);
        int cj = (int)((rec >> 32) & 255);
        float wf = __uint_as_float((unsigned)rec);
        float nm = dinv[r] * wf * dinv[b * 256 + cj];
        int pos = atomicAdd(&lcur[cj], 1);
        edat[pos] = ((unsigned long long)(unsigned)r << 32)
                  | (unsigned long long)__float_as_uint(nm);
    }
}

// ---------------- pre-MLP + xw0 -> SLICED bf16 layout xws[slice][n][8] ----------------
__global__ void pre_kernel(const float* __restrict__ x,
                           const float* __restrict__ W0, const float* __restrict__ b0,
                           const float* __restrict__ W1, const float* __restrict__ b1,
                           const float* __restrict__ Wg,
                           unsigned short* __restrict__ xws, int N) {
    int tid = blockIdx.x * blockDim.x + threadIdx.x;
    if (tid >= N * DIM) return;
    int d = tid & 31;
    int n = tid >> 5;
    float xv = x[n];
    float acc = b1[d];
#pragma unroll
    for (int k = 0; k < DIM; k++) {
        float h0 = fmaxf(xv * W0[k] + b0[k], 0.0f);
        acc += h0 * W1[k * DIM + d];
    }
    float h = fmaxf(acc, 0.0f);
    float o = 0.0f;
#pragma unroll
    for (int k = 0; k < DIM; k++) {
        float hk = __shfl(h, k, 32);
        o += hk * Wg[k * DIM + d];
    }
    xws[(size_t)(d >> 3) * N * 8 + (size_t)n * 8 + (d & 7)] = f2bf(o);
}

// ---------------- layer boundary: xws = bf16(relu(agg) @ Wg), sliced ----------------
__global__ void mid_kernel(const float* __restrict__ agg, const float* __restrict__ Wg,
                           unsigned short* __restrict__ xws, int N) {
    int tid = blockIdx.x * blockDim.x + threadIdx.x;
    if (tid >= N * DIM) return;
    int d = tid & 31;
    int n = tid >> 5;
    float h = fmaxf(agg[tid], 0.0f);
    float o = 0.0f;
#pragma unroll
    for (int k = 0; k < DIM; k++) {
        float hk = __shfl(h, k, 32);
        o += hk * Wg[k * DIM + d];
    }
    xws[(size_t)(d >> 3) * N * 8 + (size_t)n * 8 + (d & 7)] = f2bf(o);
}

// ---------------- XCD-resident sliced gather ----------------
// blockIdx&7 = XCD slot; slice = slot>>1 (2 XCDs own each 2.56-MB slice -> L2-resident).
// wave = 1 node: 16 term-slots x 4 lanes x dword (2 bf16 dims of this slice).
__global__ void gather_kernel(const unsigned short* __restrict__ xws,
                              const unsigned long long* __restrict__ edat,
                              const int* __restrict__ ptr, const float* __restrict__ dinv,
                              const float* __restrict__ bg,
                              float* __restrict__ agg, int N) {
    int bid = blockIdx.x;
    int xslot = bid & 7;
    int slice = xslot >> 1;
    int chunk = (bid >> 3) * 2 + (xslot & 1);  // 4 nodes per chunk
    int wave = threadIdx.x >> 6;
    int n = chunk * 4 + wave;
    if (n >= N) return;
    int lane = threadIdx.x & 63;
    int slot = lane >> 2;   // term slot 0..15
    int sub  = lane & 3;    // dims slice*8 + sub*2, +1
    const unsigned short* xs = xws + (size_t)slice * N * 8;
    int e0 = ptr[n], e1 = ptr[n + 1];
    int terms = e1 - e0 + 1;  // +1 self-loop
    float di = dinv[n];
    float a0 = 0.0f, a1 = 0.0f;
    for (int base = 0; base < terms; base += 16) {
        int idx = base + slot;
        int r; float nm;
        if (idx == 0) {
            r = n; nm = di * di;
        } else {
            int ee = e0 + idx - 1;
            ee = max(min(ee, e1 - 1), 0);
            unsigned long long rec = edat[ee];
            r = (int)(rec >> 32);
            nm = __uint_as_float((unsigned)rec);
        }
        if (idx >= terms) nm = 0.0f;
        unsigned u = *(const unsigned*)(xs + (size_t)r * 8 + sub * 2);  // 16-B seg/term
        a0 += nm * bf2f((unsigned short)(u & 0xFFFF));
        a1 += nm * bf2f((unsigned short)(u >> 16));
    }
    // butterfly reduce across the 16 slots (lane strides 32,16,8,4)
#pragma unroll
    for (int s = 32; s >= 4; s >>= 1) {
        a0 += __shfl_xor(a0, s, 64);
        a1 += __shfl_xor(a1, s, 64);
    }
    if (slot == 0) {
        int d0 = slice * 8 + sub * 2;
        float2 v = make_float2(a0 + bg[d0], a1 + bg[d0 + 1]);
        *(float2*)(agg + (size_t)n * DIM + d0) = v;  // 4 lanes: 32-B contiguous
    }
}

// ---------------- graph boundaries from sorted batch ----------------
__global__ void gptr_kernel(const int* __restrict__ batch, int* __restrict__ gptr, int N, int G) {
    int n = blockIdx.x * blockDim.x + threadIdx.x;
    if (n >= N) return;
    int b = batch[n];
    int bp = (n == 0) ? -1 : batch[n - 1];
    for (int g = bp + 1; g <= b; g++) gptr[g] = n;
    if (n == N - 1) {
        for (int g = b + 1; g <= G; g++) gptr[g] = N;
    }
}

// ---------------- atomic-free pool: one block per graph ----------------
__global__ void pool_kernel(const float* __restrict__ agg, const int* __restrict__ gptr,
                            float* __restrict__ sums, float* __restrict__ gcnt) {
    int g = blockIdx.x;
    int s0 = gptr[g], s1 = gptr[g + 1];
    int slot = threadIdx.x >> 5, d = threadIdx.x & 31;
    float acc = 0.0f;
    for (int n = s0 + slot; n < s1; n += 8)
        acc += fmaxf(agg[(size_t)n * DIM + d], 0.0f);
    __shared__ float red[8][DIM];
    red[slot][d] = acc;
    __syncthreads();
    if (slot == 0) {
        float t = 0.0f;
#pragma unroll
        for (int i = 0; i < 8; i++) t += red[i][d];
        sums[g * DIM + d] = t;
        if (d == 0) gcnt[g] = (float)(s1 - s0);
    }
}

// ---------------- post-MLP ----------------
__global__ void postmlp_kernel(const float* __restrict__ sums, const float* __restrict__ gcnt,
                               const float* __restrict__ W0, const float* __restrict__ b0,
                               const float* __restrict__ W1, const float* __restrict__ b1,
                               float* __restrict__ out, int G) {
    int g = blockIdx.x * blockDim.x + threadIdx.x;
    if (g >= G) return;
    float c = fmaxf(gcnt[g], 1.0f);
    float inv = 1.0f / c;
    float gv[DIM];
#pragma unroll
    for (int k = 0; k < DIM; k++) gv[k] = sums[g * DIM + k] * inv;
    float acc = b1[0];
#pragma unroll
    for (int j = 0; j < DIM; j++) {
        float p = b0[j];
#pragma unroll
        for (int k = 0; k < DIM; k++) p += gv[k] * W0[k * DIM + j];
        p = fmaxf(p, 0.0f);
        acc += p * W1[j];
    }
    out[g] = 1.0f / (1.0f + expf(-acc));
}

extern "C" void kernel_launch(void* const* d_in, const int* in_sizes, int n_in,
                              void* d_out, int out_size, void* d_ws, size_t ws_size,
                              hipStream_t stream) {
    const float* x   = (const float*)d_in[0];
    const int*   ei  = (const int*)d_in[1];
    const float* ew  = (const float*)d_in[2];
    const int*   bat = (const int*)d_in[3];
    const float* Wpre0 = (const float*)d_in[4];
    const float* bpre0 = (const float*)d_in[5];
    const float* Wpre1 = (const float*)d_in[6];
    const float* bpre1 = (const float*)d_in[7];
    const float* Wg[3]  = {(const float*)d_in[8],  (const float*)d_in[10], (const float*)d_in[12]};
    const float* bg[3]  = {(const float*)d_in[9],  (const float*)d_in[11], (const float*)d_in[13]};
    const float* Wpost0 = (const float*)d_in[14];
    const float* bpost0 = (const float*)d_in[15];
    const float* Wpost1 = (const float*)d_in[16];
    const float* bpost1 = (const float*)d_in[17];
    float* out = (float*)d_out;

    const int N = in_sizes[0];       // 160000 = 625 * 256
    const int E = in_sizes[2];       // 2560000
    const int G = out_size;          // 1024
    const int nb = (N + 255) / 256;  // 625

    const int* row = ei;
    const int* col = ei + E;

    // ---- workspace layout (float units) ----
    float* ws = (float*)d_ws;
    size_t nd = (size_t)N * DIM;
    float*          agg   = ws;                               // nd fp32
    unsigned short* xws   = (unsigned short*)(agg + nd);      // nd u16 (4 slices of N*8)
    unsigned long long* stage = (unsigned long long*)ws;      // NB*CAP u64 (alias, dead after passB2)
    float*          dinv  = ws + nd + nd / 2;                 // N
    int*            cnt   = (int*)(dinv + N);                 // N
    int*            ptr   = cnt + N;                          // N+2
    int*            bsum  = ptr + (N + 2);                    // 625 -> pad 626
    int*            gptr  = bsum + 626;                       // G+1 -> pad 1026
    int*            bcur  = gptr + 1026;                      // NB -> pad 626
    unsigned long long* edat = (unsigned long long*)(bcur + 626);  // E u64
    float*          sums  = (float*)(edat + E);               // G*DIM
    float*          gcnt  = sums + (size_t)G * DIM;           // G

    const int B = 256;
    int ndThreads = N * DIM;

    // ---- preprocessing: two-pass bucket sort ----
    init_kernel<<<(NB + B - 1) / B, B, 0, stream>>>(bcur);
    int nChunksA = (E + 8191) / 8192;
    passA_kernel<<<nChunksA, 1024, 0, stream>>>(row, col, ew, bcur, stage, E);
    passB1_kernel<<<NB, B, 0, stream>>>(stage, bcur, cnt, dinv);
    scan_block_kernel<<<nb, 256, 0, stream>>>(cnt, ptr, bsum, N);
    scan_tops_kernel<<<1, 1024, 0, stream>>>(bsum, nb);
    scan_add_kernel<<<(N + B - 1) / B, B, 0, stream>>>(ptr, bsum, N, E);
    passB2_kernel<<<NB, B, 0, stream>>>(stage, bcur, ptr, dinv, edat);

    gptr_kernel<<<(N + B - 1) / B, B, 0, stream>>>(bat, gptr, N, G);

    // ---- network ----
    pre_kernel<<<(ndThreads + B - 1) / B, B, 0, stream>>>(
        x, Wpre0, bpre0, Wpre1, bpre1, Wg[0], xws, N);

    // sliced gather grid: 4 slices x N nodes, 4 nodes/block, 8-block XCD round-robin
    int chunksPerSlice = (N + 3) / 4;            // 40000
    int gBlocks = ((chunksPerSlice + 1) / 2) * 8; // 160000

    gather_kernel<<<gBlocks, B, 0, stream>>>(xws, edat, ptr, dinv, bg[0], agg, N);
    mid_kernel<<<(ndThreads + B - 1) / B, B, 0, stream>>>(agg, Wg[1], xws, N);
    gather_kernel<<<gBlocks, B, 0, stream>>>(xws, edat, ptr, dinv, bg[1], agg, N);
    mid_kernel<<<(ndThreads + B - 1) / B, B, 0, stream>>>(agg, Wg[2], xws, N);
    gather_kernel<<<gBlocks, B, 0, stream>>>(xws, edat, ptr, dinv, bg[2], agg, N);

    pool_kernel<<<G, 256, 0, stream>>>(agg, gptr, sums, gcnt);
    postmlp_kernel<<<(G + B - 1) / B, B, 0, stream>>>(sums, gcnt, Wpost0, bpost0, Wpost1, bpost1, out, G);
}

// Round 14
// 484.332 us; speedup vs baseline: 1.8031x; 1.8031x over previous
//
#include <hip/hip_runtime.h>
#include <math.h>

#define DIM 32
#define NB 625          // buckets = N/256
#define CAP 5120        // per-bucket staging capacity

__device__ __forceinline__ unsigned short f2bf(float f) {
    unsigned u = __float_as_uint(f);
    u = (u + 0x7FFF + ((u >> 16) & 1)) >> 16;  // RNE
    return (unsigned short)u;
}
__device__ __forceinline__ float bf2f(unsigned short u) {
    return __uint_as_float(((unsigned)u) << 16);
}

// ---------------- init per-bucket staging cursors ----------------
__global__ void init_kernel(int* __restrict__ bcur) {
    int b = blockIdx.x * blockDim.x + threadIdx.x;
    if (b < NB) bcur[b] = b * CAP;
}

// ---------------- passA: bucket edges by col>>8 into staging (block=1024) ----------------
// stage rec = r(18) << 40 | (c&255) << 32 | fp32(w)
__global__ void passA_kernel(const int* __restrict__ row, const int* __restrict__ col,
                             const float* __restrict__ w, int* __restrict__ bcur,
                             unsigned long long* __restrict__ stage, int E) {
    __shared__ int hist[NB];
    __shared__ int lcur[NB];
    int base = blockIdx.x * 8192;
    for (int j = threadIdx.x; j < NB; j += 1024) hist[j] = 0;
    __syncthreads();
#pragma unroll
    for (int i = 0; i < 8; i++) {
        int e = base + i * 1024 + threadIdx.x;
        if (e < E) atomicAdd(&hist[col[e] >> 8], 1);
    }
    __syncthreads();
    for (int j = threadIdx.x; j < NB; j += 1024) {
        int h = hist[j];
        lcur[j] = h ? atomicAdd(&bcur[j], h) : 0;
    }
    __syncthreads();
#pragma unroll
    for (int i = 0; i < 8; i++) {
        int e = base + i * 1024 + threadIdx.x;
        if (e < E) {
            int c = col[e];
            int b = c >> 8;
            int pos = atomicAdd(&lcur[b], 1);
            if (pos < (b + 1) * CAP) {
                unsigned long long rec = ((unsigned long long)(unsigned)row[e] << 40)
                                       | ((unsigned long long)(unsigned)(c & 255) << 32)
                                       | (unsigned long long)__float_as_uint(w[e]);
                stage[pos] = rec;
            }
        }
    }
}

// ---------------- passB1: per-bucket col counts + weighted degree -> cnt, dinv ----------------
__global__ void passB1_kernel(const unsigned long long* __restrict__ stage,
                              const int* __restrict__ bcur,
                              int* __restrict__ cnt, float* __restrict__ dinv) {
    __shared__ int icnt[256];
    __shared__ float fdeg[256];
    int b = blockIdx.x;
    icnt[threadIdx.x] = 0;
    fdeg[threadIdx.x] = 0.0f;
    __syncthreads();
    int s0 = b * CAP;
    int m = min(bcur[b] - s0, CAP);
    for (int i = threadIdx.x; i < m; i += 256) {
        unsigned long long rec = stage[s0 + i];
        int cj = (int)((rec >> 32) & 255);
        float wf = __uint_as_float((unsigned)rec);
        atomicAdd(&icnt[cj], 1);
        atomicAdd(&fdeg[cj], wf);
    }
    __syncthreads();
    int c = b * 256 + threadIdx.x;
    cnt[c] = icnt[threadIdx.x];
    dinv[c] = rsqrtf(fdeg[threadIdx.x] + 1.0f);
}

// ---------------- scan over cnt -> ptr ----------------
__global__ void scan_block_kernel(const int* __restrict__ cnt, int* __restrict__ ptr,
                                  int* __restrict__ bsum, int N) {
    __shared__ int s[256];
    int i = blockIdx.x * 256 + threadIdx.x;
    int v = (i < N) ? cnt[i] : 0;
    s[threadIdx.x] = v;
    __syncthreads();
#pragma unroll
    for (int off = 1; off < 256; off <<= 1) {
        int t = (threadIdx.x >= off) ? s[threadIdx.x - off] : 0;
        __syncthreads();
        s[threadIdx.x] += t;
        __syncthreads();
    }
    if (i < N) ptr[i] = s[threadIdx.x] - v;
    if (threadIdx.x == 255) bsum[blockIdx.x] = s[255];
}

__global__ void scan_tops_kernel(int* __restrict__ bsum, int nb) {
    __shared__ int s[1024];
    int i = threadIdx.x;
    int v = (i < nb) ? bsum[i] : 0;
    s[i] = v;
    __syncthreads();
#pragma unroll
    for (int off = 1; off < 1024; off <<= 1) {
        int t = (i >= off) ? s[i - off] : 0;
        __syncthreads();
        s[i] += t;
        __syncthreads();
    }
    if (i < nb) bsum[i] = s[i] - v;  // exclusive
}

__global__ void scan_add_kernel(int* __restrict__ ptr, const int* __restrict__ bsum, int N, int E) {
    int i = blockIdx.x * blockDim.x + threadIdx.x;
    if (i < N) ptr[i] += bsum[i >> 8];
    if (i == 0) ptr[N] = E;
}

// ---------------- passB2: scatter staged records into CSR edat (LDS cursors) ----------------
// edat rec (u32) = r(18) << 14 | round(nm * 2^14)   (nm in [0,1))
__global__ void passB2_kernel(const unsigned long long* __restrict__ stage,
                              const int* __restrict__ bcur, const int* __restrict__ ptr,
                              const float* __restrict__ dinv,
                              unsigned* __restrict__ edat) {
    __shared__ int lcur[256];
    int b = blockIdx.x;
    lcur[threadIdx.x] = ptr[b * 256 + threadIdx.x];
    __syncthreads();
    int s0 = b * CAP;
    int m = min(bcur[b] - s0, CAP);
    for (int i = threadIdx.x; i < m; i += 256) {
        unsigned long long rec = stage[s0 + i];
        int r = (int)(rec >> 40);
        int cj = (int)((rec >> 32) & 255);
        float wf = __uint_as_float((unsigned)rec);
        float nm = dinv[r] * wf * dinv[b * 256 + cj];
        unsigned q = (unsigned)(nm * 16384.0f + 0.5f);
        q = min(q, 16383u);
        int pos = atomicAdd(&lcur[cj], 1);
        edat[pos] = ((unsigned)r << 14) | q;
    }
}

// ---------------- pre-MLP + xw0 (bf16 flat layout) ----------------
__global__ void pre_kernel(const float* __restrict__ x,
                           const float* __restrict__ W0, const float* __restrict__ b0,
                           const float* __restrict__ W1, const float* __restrict__ b1,
                           const float* __restrict__ Wg,
                           unsigned short* __restrict__ xwb, int N) {
    int tid = blockIdx.x * blockDim.x + threadIdx.x;
    if (tid >= N * DIM) return;
    int d = tid & 31;
    int n = tid >> 5;
    float xv = x[n];
    float acc = b1[d];
#pragma unroll
    for (int k = 0; k < DIM; k++) {
        float h0 = fmaxf(xv * W0[k] + b0[k], 0.0f);
        acc += h0 * W1[k * DIM + d];
    }
    float h = fmaxf(acc, 0.0f);
    float o = 0.0f;
#pragma unroll
    for (int k = 0; k < DIM; k++) {
        float hk = __shfl(h, k, 32);
        o += hk * Wg[k * DIM + d];
    }
    xwb[tid] = f2bf(o);
}

// ---------------- node-parallel CSR gather + fused boundary matmul ----------------
// wave = 1 node; 16 term-slots x 4 lanes x uint4 (8 bf16 dims) -> 16 random
// 64-B rows per vmem instruction. Butterfly allreduce over slots.
// !FINAL: h = relu(agg+bias); o = h @ Wn via shuffle-broadcast (split-k over
//         the two 32-lane halves); write next layer's xwb bf16 directly.
// FINAL:  slot 0 writes agg fp32 (+bias); pool applies relu.
template <bool FINAL>
__global__ void gather_kernel(const unsigned short* __restrict__ xwb,
                              const unsigned* __restrict__ edat,
                              const int* __restrict__ ptr, const float* __restrict__ dinv,
                              const float* __restrict__ bg, const float* __restrict__ Wn,
                              unsigned short* __restrict__ xwb_out,
                              float* __restrict__ agg, int N) {
    int wv = (blockIdx.x * blockDim.x + threadIdx.x) >> 6;
    if (wv >= N) return;
    int lane = threadIdx.x & 63;
    int slot = lane >> 2;     // 0..15: term slot
    int sub  = lane & 3;      // dims sub*8 .. sub*8+7
    int n = wv;
    int e0 = ptr[n], e1 = ptr[n + 1];
    int terms = e1 - e0 + 1;  // +1: self-loop
    float di = dinv[n];
    float acc[8] = {0, 0, 0, 0, 0, 0, 0, 0};
    for (int base = 0; base < terms; base += 16) {
        int idx = base + slot;
        int r; float nm;
        if (idx == 0) {
            r = n; nm = di * di;
        } else {
            int ee = e0 + idx - 1;
            ee = max(min(ee, e1 - 1), 0);
            unsigned rec = edat[ee];          // 64 B/wave coalesced
            r = (int)(rec >> 14);
            nm = (float)(rec & 16383u) * (1.0f / 16384.0f);
        }
        if (idx >= terms) nm = 0.0f;
        const uint4* rp = (const uint4*)(xwb + (size_t)r * DIM + sub * 8);
        uint4 u = *rp;                        // 16 random rows/wave in one instr
        acc[0] += nm * bf2f((unsigned short)(u.x & 0xFFFF));
        acc[1] += nm * bf2f((unsigned short)(u.x >> 16));
        acc[2] += nm * bf2f((unsigned short)(u.y & 0xFFFF));
        acc[3] += nm * bf2f((unsigned short)(u.y >> 16));
        acc[4] += nm * bf2f((unsigned short)(u.z & 0xFFFF));
        acc[5] += nm * bf2f((unsigned short)(u.z >> 16));
        acc[6] += nm * bf2f((unsigned short)(u.w & 0xFFFF));
        acc[7] += nm * bf2f((unsigned short)(u.w >> 16));
    }
    // butterfly allreduce across the 16 slots -> every lane holds its sub's 8 dims
#pragma unroll
    for (int s = 32; s >= 4; s >>= 1) {
#pragma unroll
        for (int i = 0; i < 8; i++) acc[i] += __shfl_xor(acc[i], s, 64);
    }
    if (FINAL) {
        if (slot == 0) {
            float4 v0 = make_float4(acc[0] + bg[sub * 8 + 0], acc[1] + bg[sub * 8 + 1],
                                    acc[2] + bg[sub * 8 + 2], acc[3] + bg[sub * 8 + 3]);
            float4 v1 = make_float4(acc[4] + bg[sub * 8 + 4], acc[5] + bg[sub * 8 + 5],
                                    acc[6] + bg[sub * 8 + 6], acc[7] + bg[sub * 8 + 7]);
            float4* dst = (float4*)(agg + (size_t)n * DIM + sub * 8);
            dst[0] = v0;
            dst[1] = v1;
        }
    } else {
        // h = relu(agg + bias), per-lane 8 dims
        float h[8];
#pragma unroll
        for (int i = 0; i < 8; i++) h[i] = fmaxf(acc[i] + bg[sub * 8 + i], 0.0f);
        // o[d] = sum_k h[k] * Wn[k][d]; split k over the two 32-lane halves.
        // h[k] lives in lane (k>>3) (lanes 0-3 hold sub 0-3) as register h[k&7].
        int d = lane & 31;
        int khalf = lane >> 5;
        float o = 0.0f;
#pragma unroll
        for (int kk = 0; kk < 16; kk++) {
            int k = khalf * 16 + kk;
            float hk = __shfl(h[kk & 7], k >> 3, 64);
            o += hk * Wn[k * DIM + d];
        }
        o += __shfl_xor(o, 32, 64);
        if (lane < 32) xwb_out[(size_t)n * DIM + d] = f2bf(o);
    }
}

// ---------------- graph boundaries from sorted batch ----------------
__global__ void gptr_kernel(const int* __restrict__ batch, int* __restrict__ gptr, int N, int G) {
    int n = blockIdx.x * blockDim.x + threadIdx.x;
    if (n >= N) return;
    int b = batch[n];
    int bp = (n == 0) ? -1 : batch[n - 1];
    for (int g = bp + 1; g <= b; g++) gptr[g] = n;
    if (n == N - 1) {
        for (int g = b + 1; g <= G; g++) gptr[g] = N;
    }
}

// ---------------- atomic-free pool: one block per graph ----------------
__global__ void pool_kernel(const float* __restrict__ agg, const int* __restrict__ gptr,
                            float* __restrict__ sums, float* __restrict__ gcnt) {
    int g = blockIdx.x;
    int s0 = gptr[g], s1 = gptr[g + 1];
    int slot = threadIdx.x >> 5, d = threadIdx.x & 31;
    float acc = 0.0f;
    for (int n = s0 + slot; n < s1; n += 8)
        acc += fmaxf(agg[(size_t)n * DIM + d], 0.0f);
    __shared__ float red[8][DIM];
    red[slot][d] = acc;
    __syncthreads();
    if (slot == 0) {
        float t = 0.0f;
#pragma unroll
        for (int i = 0; i < 8; i++) t += red[i][d];
        sums[g * DIM + d] = t;
        if (d == 0) gcnt[g] = (float)(s1 - s0);
    }
}

// ---------------- post-MLP ----------------
__global__ void postmlp_kernel(const float* __restrict__ sums, const float* __restrict__ gcnt,
                               const float* __restrict__ W0, const float* __restrict__ b0,
                               const float* __restrict__ W1, const float* __restrict__ b1,
                               float* __restrict__ out, int G) {
    int g = blockIdx.x * blockDim.x + threadIdx.x;
    if (g >= G) return;
    float c = fmaxf(gcnt[g], 1.0f);
    float inv = 1.0f / c;
    float gv[DIM];
#pragma unroll
    for (int k = 0; k < DIM; k++) gv[k] = sums[g * DIM + k] * inv;
    float acc = b1[0];
#pragma unroll
    for (int j = 0; j < DIM; j++) {
        float p = b0[j];
#pragma unroll
        for (int k = 0; k < DIM; k++) p += gv[k] * W0[k * DIM + j];
        p = fmaxf(p, 0.0f);
        acc += p * W1[j];
    }
    out[g] = 1.0f / (1.0f + expf(-acc));
}

extern "C" void kernel_launch(void* const* d_in, const int* in_sizes, int n_in,
                              void* d_out, int out_size, void* d_ws, size_t ws_size,
                              hipStream_t stream) {
    const float* x   = (const float*)d_in[0];
    const int*   ei  = (const int*)d_in[1];
    const float* ew  = (const float*)d_in[2];
    const int*   bat = (const int*)d_in[3];
    const float* Wpre0 = (const float*)d_in[4];
    const float* bpre0 = (const float*)d_in[5];
    const float* Wpre1 = (const float*)d_in[6];
    const float* bpre1 = (const float*)d_in[7];
    const float* Wg[3]  = {(const float*)d_in[8],  (const float*)d_in[10], (const float*)d_in[12]};
    const float* bg[3]  = {(const float*)d_in[9],  (const float*)d_in[11], (const float*)d_in[13]};
    const float* Wpost0 = (const float*)d_in[14];
    const float* bpost0 = (const float*)d_in[15];
    const float* Wpost1 = (const float*)d_in[16];
    const float* bpost1 = (const float*)d_in[17];
    float* out = (float*)d_out;

    const int N = in_sizes[0];       // 160000 = 625 * 256
    const int E = in_sizes[2];       // 2560000
    const int G = out_size;          // 1024
    const int nb = (N + 255) / 256;  // 625

    const int* row = ei;
    const int* col = ei + E;

    // ---- workspace layout (float units) ----
    float* ws = (float*)d_ws;
    size_t nd = (size_t)N * DIM;
    float*          agg   = ws;                               // nd fp32
    unsigned short* xwbA  = (unsigned short*)(agg + nd);      // nd u16
    unsigned short* xwbB  = xwbA + nd;                        // nd u16
    unsigned long long* stage = (unsigned long long*)ws;      // NB*CAP u64 (alias: dead before pre/gather)
    float*          dinv  = ws + nd + nd;                     // N  (after agg + 2 bf16 bufs = 2*nd floats)
    int*            cnt   = (int*)(dinv + N);                 // N
    int*            ptr   = cnt + N;                          // N+2
    int*            bsum  = ptr + (N + 2);                    // 625 -> pad 626
    int*            gptr  = bsum + 626;                       // G+1 -> pad 1026
    int*            bcur  = gptr + 1026;                      // NB -> pad 626
    unsigned*       edat  = (unsigned*)(bcur + 626);          // E u32
    float*          sums  = (float*)(edat + E);               // G*DIM
    float*          gcnt  = sums + (size_t)G * DIM;           // G

    const int B = 256;
    int ndThreads = N * DIM;

    // ---- preprocessing: two-pass bucket sort ----
    init_kernel<<<(NB + B - 1) / B, B, 0, stream>>>(bcur);
    int nChunksA = (E + 8191) / 8192;
    passA_kernel<<<nChunksA, 1024, 0, stream>>>(row, col, ew, bcur, stage, E);
    passB1_kernel<<<NB, B, 0, stream>>>(stage, bcur, cnt, dinv);
    scan_block_kernel<<<nb, 256, 0, stream>>>(cnt, ptr, bsum, N);
    scan_tops_kernel<<<1, 1024, 0, stream>>>(bsum, nb);
    scan_add_kernel<<<(N + B - 1) / B, B, 0, stream>>>(ptr, bsum, N, E);
    passB2_kernel<<<NB, B, 0, stream>>>(stage, bcur, ptr, dinv, edat);

    gptr_kernel<<<(N + B - 1) / B, B, 0, stream>>>(bat, gptr, N, G);

    // ---- network ----
    pre_kernel<<<(ndThreads + B - 1) / B, B, 0, stream>>>(
        x, Wpre0, bpre0, Wpre1, bpre1, Wg[0], xwbA, N);

    // gather grid: one wave (64 threads) per node
    long long gThreads = (long long)N * 64;
    int gBlocks = (int)((gThreads + B - 1) / B);

    // L0: gather(xwbA) + matmul Wg1 -> xwbB
    gather_kernel<false><<<gBlocks, B, 0, stream>>>(
        xwbA, edat, ptr, dinv, bg[0], Wg[1], xwbB, nullptr, N);
    // L1: gather(xwbB) + matmul Wg2 -> xwbA
    gather_kernel<false><<<gBlocks, B, 0, stream>>>(
        xwbB, edat, ptr, dinv, bg[1], Wg[2], xwbA, nullptr, N);
    // L2: gather(xwbA) -> agg (fp32, pool applies relu)
    gather_kernel<true><<<gBlocks, B, 0, stream>>>(
        xwbA, edat, ptr, dinv, bg[2], nullptr, nullptr, agg, N);

    pool_kernel<<<G, 256, 0, stream>>>(agg, gptr, sums, gcnt);
    postmlp_kernel<<<(G + B - 1) / B, B, 0, stream>>>(sums, gcnt, Wpost0, bpost0, Wpost1, bpost1, out, G);
}